// Round 9
// baseline (2825.040 us; speedup 1.0000x reference)
//
#include <hip/hip_runtime.h>
#include <hip/hip_bf16.h>

#define NPB 8192
#define NB 8
#define MQ 2048
#define FD 64
#define KN 32
#define CD 128
#define NQ (NB*MQ)
#define CAP 512
#define NCB 248                               // consumer blocks
#define NUNITS (NCB*4)                        // 992 units of 128 threads
#define QITERS ((NQ + NUNITS - 1) / NUNITS)   // 17

typedef unsigned long long ull;

// exact (non-FMA) squared distance, matching ((dx*dx + dy*dy) + dz*dz) in f32
__device__ __forceinline__ float dist2(float ax, float ay, float az,
                                       float bx, float by, float bz) {
    float dx = __fsub_rn(ax, bx);
    float dy = __fsub_rn(ay, by);
    float dz = __fsub_rn(az, bz);
    return __fadd_rn(__fadd_rn(__fmul_rn(dx, dx), __fmul_rn(dy, dy)), __fmul_rn(dz, dz));
}

// 6-step full-wave (64-lane) u64 max reduce via DPP; result valid in lane 63.
// Identity is 0 (keys are non-negative); invalid-source lanes keep old=0.
// (bit-correctness HW-verified in round 6: idx output was exact)
__device__ __forceinline__ ull dpp_max_u64(ull key) {
#define DPP_STEP(CTRL)                                                          \
    {                                                                           \
        int lo = (int)(unsigned)key, hi = (int)(key >> 32);                     \
        int lo2 = __builtin_amdgcn_update_dpp(0, lo, CTRL, 0xf, 0xf, false);    \
        int hi2 = __builtin_amdgcn_update_dpp(0, hi, CTRL, 0xf, 0xf, false);    \
        ull o = ((ull)(unsigned)hi2 << 32) | (unsigned)lo2;                     \
        if (o > key) key = o;                                                   \
    }
    DPP_STEP(0x111)  // row_shr:1
    DPP_STEP(0x112)  // row_shr:2
    DPP_STEP(0x114)  // row_shr:4
    DPP_STEP(0x118)  // row_shr:8  -> lane 15 of each row has row max
    DPP_STEP(0x142)  // row_bcast15 -> lane 31 = rows0-1 max, lane 63 = rows2-3 max
    DPP_STEP(0x143)  // row_bcast31 -> lane 63 = full-wave max
#undef DPP_STEP
    return key;
}

// ---------- presort: per cloud, sort point indices by 8^3 grid cell ----------
__global__ __launch_bounds__(512) void presort_kernel(const float* __restrict__ pos,
                                                      unsigned int* __restrict__ sorted) {
    __shared__ unsigned int skeys[NPB];    // 32 KB only
    const int b = blockIdx.x;
    const int tid = threadIdx.x;
    const float* p0 = pos + (size_t)b * NPB * 3;
    for (int i = tid; i < NPB; i += 512) {
        float x = p0[i * 3 + 0];
        float y = p0[i * 3 + 1];
        float z = p0[i * 3 + 2];
        int cx = min(7, max(0, (int)(x * 8.0f)));
        int cy = min(7, max(0, (int)(y * 8.0f)));
        int cz = min(7, max(0, (int)(z * 8.0f)));
        unsigned cell = ((unsigned)cz << 6) | ((unsigned)cy << 3) | (unsigned)cx;
        skeys[i] = (cell << 13) | (unsigned)i;
    }
    __syncthreads();
    for (unsigned k = 2; k <= NPB; k <<= 1) {
        for (unsigned j = k >> 1; j > 0; j >>= 1) {
            for (unsigned i = tid; i < NPB / 2; i += 512) {
                unsigned a = ((i & ~(j - 1)) << 1) | (i & (j - 1));
                unsigned c = a | j;
                unsigned x = skeys[a], y = skeys[c];
                bool up = ((a & k) == 0);
                if ((x > y) == up) { skeys[a] = y; skeys[c] = x; }
            }
            __syncthreads();
        }
    }
    for (int i = tid; i < NPB; i += 512)
        sorted[b * NPB + i] = skeys[i] & (NPB - 1);
}

struct FpsSM {
    float sx[NPB], sy[NPB], sz[NPB];   // 96 KB, ORIGINAL index order
    ull part[2][8];                    // double-buffered wave partials
    __align__(16) int stage[8];        // staged samples (flushed every 8 iters)
};
struct UnitSM {
    float msg[KN][68];                 // 8704 B, 16-aligned (first member)
    ull buf[CAP];                      // 4096 B
    int nb[KN];
    int scnt;
    int pad;
};
union SMU {
    FpsSM f;
    UnitSM u[4];
};

__global__ __launch_bounds__(512) void mega_kernel(const float* __restrict__ xin,
                                                   const float* __restrict__ pos,
                                                   const float* __restrict__ W1,
                                                   const float* __restrict__ b1,
                                                   const unsigned int* __restrict__ sorted,
                                                   int* __restrict__ samp,
                                                   int* __restrict__ progress,
                                                   float* __restrict__ out) {
    __shared__ SMU sm;
    const int tid = threadIdx.x;

    if (blockIdx.x < NB) {
        // ======================= FPS producer (blocks 0..7) =======================
        const int b = blockIdx.x;
        const int wv = tid >> 6, lane = tid & 63;
        const float* p0 = pos + (size_t)b * NPB * 3;

        for (int i = tid; i < NPB; i += 512) {
            sm.f.sx[i] = p0[i * 3 + 0];
            sm.f.sy[i] = p0[i * 3 + 1];
            sm.f.sz[i] = p0[i * 3 + 2];
        }
        __syncthreads();

        // ---- each thread takes 16 spatially-contiguous points into registers ----
        const unsigned int* sp = sorted + b * NPB + tid * 16;
        float px[16], py[16], pz[16], dmin[16];
        unsigned orig[16];
        float bx0 = __builtin_huge_valf(), bx1 = -__builtin_huge_valf();
        float by0 = __builtin_huge_valf(), by1 = -__builtin_huge_valf();
        float bz0 = __builtin_huge_valf(), bz1 = -__builtin_huge_valf();
        #pragma unroll
        for (int j = 0; j < 16; j++) {
            unsigned o = sp[j] & (NPB - 1);
            orig[j] = o;
            float x = sm.f.sx[o], y = sm.f.sy[o], z = sm.f.sz[o];
            px[j] = x; py[j] = y; pz[j] = z;
            dmin[j] = __builtin_huge_valf();
            bx0 = fminf(bx0, x); bx1 = fmaxf(bx1, x);
            by0 = fminf(by0, y); by1 = fmaxf(by1, y);
            bz0 = fminf(bz0, z); bz1 = fmaxf(bz1, z);
        }
        ull mykey = ((ull)0x7f800000u << 32);   // dmin part = +INF -> scans at t=0
        ull wpart = 0;                          // lane 63's cached wave partial
        __syncthreads();

        for (int t = 0; t < MQ; t++) {
            int last;
            if (t) {
                const ull* pp = sm.f.part[(t - 1) & 1];
                ull g = pp[0];
                #pragma unroll
                for (int i = 1; i < 8; i++) { ull o = pp[i]; g = (o > g) ? o : g; }
                last = ((int)(~(unsigned)g)) & (NPB - 1);
            } else {
                last = 0;
            }
            if (tid == 0) {
                sm.f.stage[t & 7] = last;
                if ((t & 7) == 7) {
                    // flush 8 staged samples with 2 vector stores, then publish.
                    int4 lo = *(const int4*)&sm.f.stage[0];
                    int4 hi = *(const int4*)&sm.f.stage[4];
                    *(int4*)&samp[b * MQ + (t - 7)] = lo;
                    *(int4*)&samp[b * MQ + (t - 3)] = hi;
                    __hip_atomic_store(&progress[b], t + 1, __ATOMIC_RELEASE,
                                       __HIP_MEMORY_SCOPE_AGENT);
                }
            }
            float lx = sm.f.sx[last], ly = sm.f.sy[last], lz = sm.f.sz[last];

            // conservative lower bound of d2(last, any point in this thread's bbox)
            float ddx = fmaxf(fmaxf(bx0 - lx, lx - bx1), 0.0f);
            float ddy = fmaxf(fmaxf(by0 - ly, ly - by1), 0.0f);
            float ddz = fmaxf(fmaxf(bz0 - lz, lz - bz1), 0.0f);
            float dlb = ddx * ddx + ddy * ddy + ddz * ddz;
            float cm = __uint_as_float((unsigned)(mykey >> 32));
            bool active = (__fmul_rn(0.999f, dlb) < cm);

            if (__ballot(active)) {           // wave-uniform: any lane needs a scan
                if (active) {
                    ull bestk = 0;
                    #pragma unroll
                    for (int j = 0; j < 16; j++) {
                        float d = dist2(px[j], py[j], pz[j], lx, ly, lz);
                        float dm = fminf(dmin[j], d);
                        dmin[j] = dm;
                        ull kj = ((ull)__float_as_uint(dm) << 32) | (unsigned)(~orig[j]);
                        if (kj > bestk) bestk = kj;
                    }
                    mykey = bestk;
                }
                wpart = dpp_max_u64(mykey);   // all 64 lanes participate
            }
            // pruned wave: no lane's dmin changed -> cached wpart still exact
            if (lane == 63) sm.f.part[t & 1][wv] = wpart;
            __syncthreads();
        }
        return;
    }

    // ================== consumers: ball query + MLP + tail outputs ==================
    const int c = blockIdx.x - NB;         // 0..247
    const int unit = tid >> 7;             // 0..3
    const int ut = tid & 127;              // thread-in-unit
    UnitSM& U = sm.u[unit];
    const int g = c * 4 + unit;            // global unit id, 0..991
    const float RR = (float)(0.1 * 0.1);

    // per-channel weights, hoisted across queries
    float w[68];
    #pragma unroll
    for (int f = 0; f < 67; f++) w[f] = W1[f * CD + ut];
    w[67] = 0.0f;
    const float bias = b1[ut];

    for (int qi = 0; qi < QITERS; qi++) {
        const int q = g + qi * NUNITS;
        const bool active = q < NQ;
        int b = 0, s = 0;
        const float* P = pos;
        float qx = 0.f, qy = 0.f, qz = 0.f;

        if (active) {
            b = q >> 11;
            const int tq = q & (MQ - 1);
            while (__hip_atomic_load(&progress[b], __ATOMIC_ACQUIRE,
                                     __HIP_MEMORY_SCOPE_AGENT) < tq + 1)
                __builtin_amdgcn_s_sleep(64);
            s = samp[q] & (NPB - 1);
            P = pos + (size_t)b * NPB * 3;
            qx = P[s * 3 + 0]; qy = P[s * 3 + 1]; qz = P[s * 3 + 2];
        }
        if (ut == 0) U.scnt = 0;
        __syncthreads();                                   // barrier 1

        if (active) {
            for (int p = ut; p < NPB; p += 128) {
                float xx = P[p * 3 + 0];
                float yy = P[p * 3 + 1];
                float zz = P[p * 3 + 2];
                float d2v = dist2(qx, qy, qz, xx, yy, zz);
                if (d2v <= RR) {
                    int slot = atomicAdd(&U.scnt, 1);
                    if (slot < CAP)
                        U.buf[slot] = ((ull)__float_as_uint(d2v) << 32) | (unsigned)p;
                }
            }
        }
        __syncthreads();                                   // barrier 2

        int n = 0, nk = 0;
        if (active) {
            n = U.scnt; if (n > CAP) n = CAP;
            nk = (n < KN) ? n : KN;
        }
        if (active && ut < 64) {
            if (n <= 64) {
                // fast path: 64-key bitonic sort in the unit's first wave
                ull key = (ut < n) ? U.buf[ut] : ~0ULL;
                #pragma unroll
                for (int k = 2; k <= 64; k <<= 1) {
                    #pragma unroll
                    for (int j = k >> 1; j > 0; j >>= 1) {
                        ull o = __shfl_xor(key, (unsigned)j, 64);
                        bool ascending = ((ut & k) == 0);
                        bool upper = ((ut & j) != 0);
                        bool keepMin = (ascending != upper);
                        ull mn = (o < key) ? o : key;
                        ull mx = (o < key) ? key : o;
                        key = keepMin ? mn : mx;
                    }
                }
                if (ut < nk) U.nb[ut] = ((int)(unsigned)key) & (NPB - 1);
            } else {
                // slow path (rare): nk rounds of wave-min selection
                ull ck[CAP / 64];
                #pragma unroll
                for (int i = 0; i < CAP / 64; i++) {
                    int sl = ut + i * 64;
                    ck[i] = (sl < n) ? U.buf[sl] : ~0ULL;
                }
                for (int r = 0; r < nk; r++) {
                    ull lm = ck[0];
                    int li = 0;
                    #pragma unroll
                    for (int i = 1; i < CAP / 64; i++) {
                        if (ck[i] < lm) { lm = ck[i]; li = i; }
                    }
                    ull gm = lm;
                    #pragma unroll
                    for (int off = 1; off < 64; off <<= 1) {
                        ull o = __shfl_xor(gm, off, 64);
                        gm = (o < gm) ? o : gm;
                    }
                    ull won = __ballot(lm == gm);
                    int wlane = __ffsll((long long)won) - 1;
                    if (ut == wlane) ck[li] = ~0ULL;
                    if (ut == 0) U.nb[r] = ((int)(unsigned)gm) & (NPB - 1);
                }
            }
        }
        __syncthreads();                                   // barrier 3

        if (active) {
            const int lane64 = ut & 63, half = ut >> 6;
            for (int k = half; k < nk; k += 2) {
                int p = U.nb[k];
                U.msg[k][lane64] = xin[((size_t)(b * NPB + p)) * FD + lane64];
            }
            if (ut < nk) {
                int p = U.nb[ut];
                U.msg[ut][64] = __fsub_rn(P[p * 3 + 0], qx);
                U.msg[ut][65] = __fsub_rn(P[p * 3 + 1], qy);
                U.msg[ut][66] = __fsub_rn(P[p * 3 + 2], qz);
                U.msg[ut][67] = 0.0f;
            }
        }
        __syncthreads();                                   // barrier 4

        if (active) {
            float acc = 0.0f;   // relu >= 0 and nk >= 1 (self), so 0 is the max identity
            for (int k = 0; k < nk; k++) {
                float s0 = 0.f, s1 = 0.f, s2 = 0.f, s3 = 0.f;
                #pragma unroll
                for (int f4 = 0; f4 < 17; f4++) {
                    float4 mv = *(const float4*)&U.msg[k][f4 * 4];
                    s0 = fmaf(mv.x, w[f4 * 4 + 0], s0);
                    s1 = fmaf(mv.y, w[f4 * 4 + 1], s1);
                    s2 = fmaf(mv.z, w[f4 * 4 + 2], s2);
                    s3 = fmaf(mv.w, w[f4 * 4 + 3], s3);
                }
                float h = (s0 + s1) + (s2 + s3) + bias;
                h = fmaxf(h, 0.0f);
                acc = fmaxf(acc, h);
            }
            out[(size_t)q * CD + ut] = acc;
            if (ut == 0) {
                float* qp = out + (size_t)NQ * CD;
                qp[q * 3 + 0] = qx;
                qp[q * 3 + 1] = qy;
                qp[q * 3 + 2] = qz;
                float* bo = qp + (size_t)NQ * 3;
                bo[q] = (float)b;
                float* io = bo + NQ;
                io[q] = (float)(b * NPB + s);
            }
        }
    }
}

extern "C" void kernel_launch(void* const* d_in, const int* in_sizes, int n_in,
                              void* d_out, int out_size, void* d_ws, size_t ws_size,
                              hipStream_t stream) {
    const float* x   = (const float*)d_in[0];
    const float* pos = (const float*)d_in[1];
    const float* W1  = (const float*)d_in[3];
    const float* b1  = (const float*)d_in[4];
    float* out = (float*)d_out;

    int* samp = (int*)d_ws;                     // NQ ints
    int* progress = samp + NQ;                  // NB ints
    unsigned int* sorted = (unsigned int*)(progress + NB);   // NB*NPB u32

    hipMemsetAsync(progress, 0, NB * sizeof(int), stream);
    presort_kernel<<<NB, 512, 0, stream>>>(pos, sorted);
    mega_kernel<<<NB + NCB, 512, 0, stream>>>(x, pos, W1, b1, sorted, samp, progress, out);
}

// Round 10
// 2326.325 us; speedup vs baseline: 1.2144x; 1.2144x over previous
//
#include <hip/hip_runtime.h>
#include <hip/hip_bf16.h>

#define NPB 8192
#define NB 8
#define MQ 2048
#define FD 64
#define KN 32
#define CD 128
#define NQ (NB*MQ)
#define CAP 512
#define NCB 248                               // consumer blocks
#define NUNITS (NCB*4)                        // 992 units of 128 threads
#define QITERS ((NQ + NUNITS - 1) / NUNITS)   // 17

typedef unsigned long long ull;

// LDS-only block barrier: orders LDS ops across the block WITHOUT draining
// vmcnt (global stores keep flying). Only LDS data (part[]) crosses this
// barrier in the FPS loop, so lgkmcnt(0) is sufficient.
#define LDS_BARRIER() asm volatile("s_waitcnt lgkmcnt(0)\n\ts_barrier" ::: "memory")

// exact (non-FMA) squared distance, matching ((dx*dx + dy*dy) + dz*dz) in f32
__device__ __forceinline__ float dist2(float ax, float ay, float az,
                                       float bx, float by, float bz) {
    float dx = __fsub_rn(ax, bx);
    float dy = __fsub_rn(ay, by);
    float dz = __fsub_rn(az, bz);
    return __fadd_rn(__fadd_rn(__fmul_rn(dx, dx), __fmul_rn(dy, dy)), __fmul_rn(dz, dz));
}

// 6-step full-wave (64-lane) u64 max reduce via DPP; result valid in lane 63.
__device__ __forceinline__ ull dpp_max_u64(ull key) {
#define DPP_STEP(CTRL)                                                          \
    {                                                                           \
        int lo = (int)(unsigned)key, hi = (int)(key >> 32);                     \
        int lo2 = __builtin_amdgcn_update_dpp(0, lo, CTRL, 0xf, 0xf, false);    \
        int hi2 = __builtin_amdgcn_update_dpp(0, hi, CTRL, 0xf, 0xf, false);    \
        ull o = ((ull)(unsigned)hi2 << 32) | (unsigned)lo2;                     \
        if (o > key) key = o;                                                   \
    }
    DPP_STEP(0x111)  // row_shr:1
    DPP_STEP(0x112)  // row_shr:2
    DPP_STEP(0x114)  // row_shr:4
    DPP_STEP(0x118)  // row_shr:8
    DPP_STEP(0x142)  // row_bcast15
    DPP_STEP(0x143)  // row_bcast31
#undef DPP_STEP
    return key;
}

// ---------- presort: per cloud, sort point indices by 8^3 grid cell ----------
__global__ __launch_bounds__(512) void presort_kernel(const float* __restrict__ pos,
                                                      unsigned int* __restrict__ sorted) {
    __shared__ unsigned int skeys[NPB];    // 32 KB only
    const int b = blockIdx.x;
    const int tid = threadIdx.x;
    const float* p0 = pos + (size_t)b * NPB * 3;
    for (int i = tid; i < NPB; i += 512) {
        float x = p0[i * 3 + 0];
        float y = p0[i * 3 + 1];
        float z = p0[i * 3 + 2];
        int cx = min(7, max(0, (int)(x * 8.0f)));
        int cy = min(7, max(0, (int)(y * 8.0f)));
        int cz = min(7, max(0, (int)(z * 8.0f)));
        unsigned cell = ((unsigned)cz << 6) | ((unsigned)cy << 3) | (unsigned)cx;
        skeys[i] = (cell << 13) | (unsigned)i;
    }
    __syncthreads();
    for (unsigned k = 2; k <= NPB; k <<= 1) {
        for (unsigned j = k >> 1; j > 0; j >>= 1) {
            for (unsigned i = tid; i < NPB / 2; i += 512) {
                unsigned a = ((i & ~(j - 1)) << 1) | (i & (j - 1));
                unsigned c = a | j;
                unsigned x = skeys[a], y = skeys[c];
                bool up = ((a & k) == 0);
                if ((x > y) == up) { skeys[a] = y; skeys[c] = x; }
            }
            __syncthreads();
        }
    }
    for (int i = tid; i < NPB; i += 512)
        sorted[b * NPB + i] = skeys[i] & (NPB - 1);
}

struct FpsSM {
    float sx[NPB], sy[NPB], sz[NPB];   // 96 KB, ORIGINAL index order
    ull part[2][8];                    // double-buffered wave partials
};
struct UnitSM {
    float msg[KN][68];                 // 8704 B, 16-aligned (first member)
    ull buf[CAP];                      // 4096 B
    int nb[KN];
    int scnt;
    int pad;
};
union SMU {
    FpsSM f;
    UnitSM u[4];
};

__global__ __launch_bounds__(512) void mega_kernel(const float* __restrict__ xin,
                                                   const float* __restrict__ pos,
                                                   const float* __restrict__ W1,
                                                   const float* __restrict__ b1,
                                                   const unsigned int* __restrict__ sorted,
                                                   int* __restrict__ samp,
                                                   int* __restrict__ progress,
                                                   float* __restrict__ out) {
    __shared__ SMU sm;
    const int tid = threadIdx.x;

    if (blockIdx.x < NB) {
        // ======================= FPS producer (blocks 0..7) =======================
        const int b = blockIdx.x;
        const int wv = tid >> 6, lane = tid & 63;
        const float* p0 = pos + (size_t)b * NPB * 3;

        for (int i = tid; i < NPB; i += 512) {
            sm.f.sx[i] = p0[i * 3 + 0];
            sm.f.sy[i] = p0[i * 3 + 1];
            sm.f.sz[i] = p0[i * 3 + 2];
        }
        __syncthreads();

        // ---- each thread takes 16 spatially-contiguous points into registers ----
        const unsigned int* sp = sorted + b * NPB + tid * 16;
        float px[16], py[16], pz[16], dmin[16];
        unsigned orig[16];
        float bx0 = __builtin_huge_valf(), bx1 = -__builtin_huge_valf();
        float by0 = __builtin_huge_valf(), by1 = -__builtin_huge_valf();
        float bz0 = __builtin_huge_valf(), bz1 = -__builtin_huge_valf();
        #pragma unroll
        for (int j = 0; j < 16; j++) {
            unsigned o = sp[j] & (NPB - 1);
            orig[j] = o;
            float x = sm.f.sx[o], y = sm.f.sy[o], z = sm.f.sz[o];
            px[j] = x; py[j] = y; pz[j] = z;
            dmin[j] = __builtin_huge_valf();
            bx0 = fminf(bx0, x); bx1 = fmaxf(bx1, x);
            by0 = fminf(by0, y); by1 = fmaxf(by1, y);
            bz0 = fminf(bz0, z); bz1 = fmaxf(bz1, z);
        }
        ull mykey = ((ull)0x7f800000u << 32);   // dmin part = +INF -> scans at t=0
        __syncthreads();

        for (int t = 0; t < MQ; t++) {
            int last;
            if (t) {
                const ull* pp = sm.f.part[(t - 1) & 1];
                ull g = pp[0];
                #pragma unroll
                for (int i = 1; i < 8; i++) { ull o = pp[i]; g = (o > g) ? o : g; }
                last = ((int)(~(unsigned)g)) & (NPB - 1);
            } else {
                last = 0;
            }
            // wave 7 owns output publication: plain store per iter (latency hidden
            // by the vmcnt-free barrier), release-publish every 16 iters.
            if (tid == 448) {
                samp[b * MQ + t] = last;
                if ((t & 15) == 15)
                    __hip_atomic_store(&progress[b], t + 1, __ATOMIC_RELEASE,
                                       __HIP_MEMORY_SCOPE_AGENT);
            }
            float lx = sm.f.sx[last], ly = sm.f.sy[last], lz = sm.f.sz[last];

            // conservative lower bound of d2(last, any point in this thread's bbox)
            float ddx = fmaxf(fmaxf(bx0 - lx, lx - bx1), 0.0f);
            float ddy = fmaxf(fmaxf(by0 - ly, ly - by1), 0.0f);
            float ddz = fmaxf(fmaxf(bz0 - lz, lz - bz1), 0.0f);
            float dlb = ddx * ddx + ddy * ddy + ddz * ddz;
            float cm = __uint_as_float((unsigned)(mykey >> 32));

            if (__fmul_rn(0.999f, dlb) < cm) {
                ull bestk = 0;
                #pragma unroll
                for (int j = 0; j < 16; j++) {
                    float d = dist2(px[j], py[j], pz[j], lx, ly, lz);
                    float dm = fminf(dmin[j], d);
                    dmin[j] = dm;
                    ull kj = ((ull)__float_as_uint(dm) << 32) | (unsigned)(~orig[j]);
                    if (kj > bestk) bestk = kj;
                }
                mykey = bestk;
            }
            ull w = dpp_max_u64(mykey);
            if (lane == 63) sm.f.part[t & 1][wv] = w;
            LDS_BARRIER();   // orders the LDS partials; does NOT drain global stores
        }
        return;
    }

    // ================== consumers: ball query + MLP + tail outputs ==================
    const int c = blockIdx.x - NB;         // 0..247
    const int unit = tid >> 7;             // 0..3
    const int ut = tid & 127;              // thread-in-unit
    UnitSM& U = sm.u[unit];
    const int g = c * 4 + unit;            // global unit id, 0..991
    const float RR = (float)(0.1 * 0.1);

    // per-channel weights, hoisted across queries
    float w[68];
    #pragma unroll
    for (int f = 0; f < 67; f++) w[f] = W1[f * CD + ut];
    w[67] = 0.0f;
    const float bias = b1[ut];

    for (int qi = 0; qi < QITERS; qi++) {
        const int q = g + qi * NUNITS;
        const bool active = q < NQ;
        int b = 0, s = 0;
        const float* P = pos;
        float qx = 0.f, qy = 0.f, qz = 0.f;

        if (active) {
            b = q >> 11;
            const int tq = q & (MQ - 1);
            while (__hip_atomic_load(&progress[b], __ATOMIC_ACQUIRE,
                                     __HIP_MEMORY_SCOPE_AGENT) < tq + 1)
                __builtin_amdgcn_s_sleep(16);
            s = samp[q] & (NPB - 1);
            P = pos + (size_t)b * NPB * 3;
            qx = P[s * 3 + 0]; qy = P[s * 3 + 1]; qz = P[s * 3 + 2];
        }
        if (ut == 0) U.scnt = 0;
        __syncthreads();                                   // barrier 1

        if (active) {
            for (int p = ut; p < NPB; p += 128) {
                float xx = P[p * 3 + 0];
                float yy = P[p * 3 + 1];
                float zz = P[p * 3 + 2];
                float d2v = dist2(qx, qy, qz, xx, yy, zz);
                if (d2v <= RR) {
                    int slot = atomicAdd(&U.scnt, 1);
                    if (slot < CAP)
                        U.buf[slot] = ((ull)__float_as_uint(d2v) << 32) | (unsigned)p;
                }
            }
        }
        __syncthreads();                                   // barrier 2

        int n = 0, nk = 0;
        if (active) {
            n = U.scnt; if (n > CAP) n = CAP;
            nk = (n < KN) ? n : KN;
        }
        if (active && ut < 64) {
            if (n <= 64) {
                // fast path: 64-key bitonic sort in the unit's first wave
                ull key = (ut < n) ? U.buf[ut] : ~0ULL;
                #pragma unroll
                for (int k = 2; k <= 64; k <<= 1) {
                    #pragma unroll
                    for (int j = k >> 1; j > 0; j >>= 1) {
                        ull o = __shfl_xor(key, (unsigned)j, 64);
                        bool ascending = ((ut & k) == 0);
                        bool upper = ((ut & j) != 0);
                        bool keepMin = (ascending != upper);
                        ull mn = (o < key) ? o : key;
                        ull mx = (o < key) ? key : o;
                        key = keepMin ? mn : mx;
                    }
                }
                if (ut < nk) U.nb[ut] = ((int)(unsigned)key) & (NPB - 1);
            } else {
                // slow path (rare): nk rounds of wave-min selection
                ull ck[CAP / 64];
                #pragma unroll
                for (int i = 0; i < CAP / 64; i++) {
                    int sl = ut + i * 64;
                    ck[i] = (sl < n) ? U.buf[sl] : ~0ULL;
                }
                for (int r = 0; r < nk; r++) {
                    ull lm = ck[0];
                    int li = 0;
                    #pragma unroll
                    for (int i = 1; i < CAP / 64; i++) {
                        if (ck[i] < lm) { lm = ck[i]; li = i; }
                    }
                    ull gm = lm;
                    #pragma unroll
                    for (int off = 1; off < 64; off <<= 1) {
                        ull o = __shfl_xor(gm, off, 64);
                        gm = (o < gm) ? o : gm;
                    }
                    ull won = __ballot(lm == gm);
                    int wlane = __ffsll((long long)won) - 1;
                    if (ut == wlane) ck[li] = ~0ULL;
                    if (ut == 0) U.nb[r] = ((int)(unsigned)gm) & (NPB - 1);
                }
            }
        }
        __syncthreads();                                   // barrier 3

        if (active) {
            const int lane64 = ut & 63, half = ut >> 6;
            for (int k = half; k < nk; k += 2) {
                int p = U.nb[k];
                U.msg[k][lane64] = xin[((size_t)(b * NPB + p)) * FD + lane64];
            }
            if (ut < nk) {
                int p = U.nb[ut];
                U.msg[ut][64] = __fsub_rn(P[p * 3 + 0], qx);
                U.msg[ut][65] = __fsub_rn(P[p * 3 + 1], qy);
                U.msg[ut][66] = __fsub_rn(P[p * 3 + 2], qz);
                U.msg[ut][67] = 0.0f;
            }
        }
        __syncthreads();                                   // barrier 4

        if (active) {
            float acc = 0.0f;   // relu >= 0 and nk >= 1 (self), so 0 is the max identity
            for (int k = 0; k < nk; k++) {
                float s0 = 0.f, s1 = 0.f, s2 = 0.f, s3 = 0.f;
                #pragma unroll
                for (int f4 = 0; f4 < 17; f4++) {
                    float4 mv = *(const float4*)&U.msg[k][f4 * 4];
                    s0 = fmaf(mv.x, w[f4 * 4 + 0], s0);
                    s1 = fmaf(mv.y, w[f4 * 4 + 1], s1);
                    s2 = fmaf(mv.z, w[f4 * 4 + 2], s2);
                    s3 = fmaf(mv.w, w[f4 * 4 + 3], s3);
                }
                float h = (s0 + s1) + (s2 + s3) + bias;
                h = fmaxf(h, 0.0f);
                acc = fmaxf(acc, h);
            }
            out[(size_t)q * CD + ut] = acc;
            if (ut == 0) {
                float* qp = out + (size_t)NQ * CD;
                qp[q * 3 + 0] = qx;
                qp[q * 3 + 1] = qy;
                qp[q * 3 + 2] = qz;
                float* bo = qp + (size_t)NQ * 3;
                bo[q] = (float)b;
                float* io = bo + NQ;
                io[q] = (float)(b * NPB + s);
            }
        }
    }
}

extern "C" void kernel_launch(void* const* d_in, const int* in_sizes, int n_in,
                              void* d_out, int out_size, void* d_ws, size_t ws_size,
                              hipStream_t stream) {
    const float* x   = (const float*)d_in[0];
    const float* pos = (const float*)d_in[1];
    const float* W1  = (const float*)d_in[3];
    const float* b1  = (const float*)d_in[4];
    float* out = (float*)d_out;

    int* samp = (int*)d_ws;                     // NQ ints
    int* progress = samp + NQ;                  // NB ints
    unsigned int* sorted = (unsigned int*)(progress + NB);   // NB*NPB u32

    hipMemsetAsync(progress, 0, NB * sizeof(int), stream);
    presort_kernel<<<NB, 512, 0, stream>>>(pos, sorted);
    mega_kernel<<<NB + NCB, 512, 0, stream>>>(x, pos, W1, b1, sorted, samp, progress, out);
}

// Round 11
// 2320.886 us; speedup vs baseline: 1.2172x; 1.0023x over previous
//
#include <hip/hip_runtime.h>
#include <hip/hip_bf16.h>

#define NPB 8192
#define NB 8
#define MQ 2048
#define FD 64
#define KN 32
#define CD 128
#define NQ (NB*MQ)
#define CAP 512
#define NCB 248                               // consumer blocks
#define NUNITS (NCB*4)                        // 992 units of 128 threads
#define QITERS ((NQ + NUNITS - 1) / NUNITS)   // 17

typedef unsigned long long ull;

// LDS-only block barrier: orders LDS ops across the block WITHOUT draining
// vmcnt (global stores keep flying). Only LDS data (part[]) crosses this
// barrier in the FPS loop, so lgkmcnt(0) is sufficient.
#define LDS_BARRIER() asm volatile("s_waitcnt lgkmcnt(0)\n\ts_barrier" ::: "memory")

// exact (non-FMA) squared distance, matching ((dx*dx + dy*dy) + dz*dz) in f32
__device__ __forceinline__ float dist2(float ax, float ay, float az,
                                       float bx, float by, float bz) {
    float dx = __fsub_rn(ax, bx);
    float dy = __fsub_rn(ay, by);
    float dz = __fsub_rn(az, bz);
    return __fadd_rn(__fadd_rn(__fmul_rn(dx, dx), __fmul_rn(dy, dy)), __fmul_rn(dz, dz));
}

// 6-step full-wave (64-lane) u64 max reduce via DPP; result valid in lane 63.
__device__ __forceinline__ ull dpp_max_u64(ull key) {
#define DPP_STEP(CTRL)                                                          \
    {                                                                           \
        int lo = (int)(unsigned)key, hi = (int)(key >> 32);                     \
        int lo2 = __builtin_amdgcn_update_dpp(0, lo, CTRL, 0xf, 0xf, false);    \
        int hi2 = __builtin_amdgcn_update_dpp(0, hi, CTRL, 0xf, 0xf, false);    \
        ull o = ((ull)(unsigned)hi2 << 32) | (unsigned)lo2;                     \
        if (o > key) key = o;                                                   \
    }
    DPP_STEP(0x111)  // row_shr:1
    DPP_STEP(0x112)  // row_shr:2
    DPP_STEP(0x114)  // row_shr:4
    DPP_STEP(0x118)  // row_shr:8
    DPP_STEP(0x142)  // row_bcast15
    DPP_STEP(0x143)  // row_bcast31
#undef DPP_STEP
    return key;
}

// ---------- presort: per cloud, sort point indices by 8^3 grid cell ----------
__global__ __launch_bounds__(512) void presort_kernel(const float* __restrict__ pos,
                                                      unsigned int* __restrict__ sorted) {
    __shared__ unsigned int skeys[NPB];    // 32 KB only
    const int b = blockIdx.x;
    const int tid = threadIdx.x;
    const float* p0 = pos + (size_t)b * NPB * 3;
    for (int i = tid; i < NPB; i += 512) {
        float x = p0[i * 3 + 0];
        float y = p0[i * 3 + 1];
        float z = p0[i * 3 + 2];
        int cx = min(7, max(0, (int)(x * 8.0f)));
        int cy = min(7, max(0, (int)(y * 8.0f)));
        int cz = min(7, max(0, (int)(z * 8.0f)));
        unsigned cell = ((unsigned)cz << 6) | ((unsigned)cy << 3) | (unsigned)cx;
        skeys[i] = (cell << 13) | (unsigned)i;
    }
    __syncthreads();
    for (unsigned k = 2; k <= NPB; k <<= 1) {
        for (unsigned j = k >> 1; j > 0; j >>= 1) {
            for (unsigned i = tid; i < NPB / 2; i += 512) {
                unsigned a = ((i & ~(j - 1)) << 1) | (i & (j - 1));
                unsigned c = a | j;
                unsigned x = skeys[a], y = skeys[c];
                bool up = ((a & k) == 0);
                if ((x > y) == up) { skeys[a] = y; skeys[c] = x; }
            }
            __syncthreads();
        }
    }
    for (int i = tid; i < NPB; i += 512)
        sorted[b * NPB + i] = skeys[i] & (NPB - 1);
}

struct FpsSM {
    float2 sxy[NPB];                   // 64 KB
    float sz[NPB];                     // 32 KB
    __align__(16) ull part[2][8];      // double-buffered wave partials
};
struct UnitSM {
    float msg[KN][68];                 // 8704 B, 16-aligned (first member)
    ull buf[CAP];                      // 4096 B
    int nb[KN];
    int scnt;
    int pad;
};
union SMU {
    FpsSM f;
    UnitSM u[4];
};

__global__ __launch_bounds__(512) void mega_kernel(const float* __restrict__ xin,
                                                   const float* __restrict__ pos,
                                                   const float* __restrict__ W1,
                                                   const float* __restrict__ b1,
                                                   const unsigned int* __restrict__ sorted,
                                                   int* __restrict__ samp,
                                                   int* __restrict__ progress,
                                                   float* __restrict__ out) {
    __shared__ SMU sm;
    const int tid = threadIdx.x;

    if (blockIdx.x < NB) {
        // ======================= FPS producer (blocks 0..7) =======================
        const int b = blockIdx.x;
        const int wv = tid >> 6, lane = tid & 63;
        const float* p0 = pos + (size_t)b * NPB * 3;

        for (int i = tid; i < NPB; i += 512) {
            float x = p0[i * 3 + 0];
            float y = p0[i * 3 + 1];
            float z = p0[i * 3 + 2];
            sm.f.sxy[i] = make_float2(x, y);
            sm.f.sz[i] = z;
        }
        __syncthreads();

        // ---- each thread takes 16 spatially-contiguous points into registers ----
        const unsigned int* sp = sorted + b * NPB + tid * 16;
        float px[16], py[16], pz[16], dmin[16];
        unsigned orig[16];
        float bx0 = __builtin_huge_valf(), bx1 = -__builtin_huge_valf();
        float by0 = __builtin_huge_valf(), by1 = -__builtin_huge_valf();
        float bz0 = __builtin_huge_valf(), bz1 = -__builtin_huge_valf();
        #pragma unroll
        for (int j = 0; j < 16; j++) {
            unsigned o = sp[j] & (NPB - 1);
            orig[j] = o;
            float2 xy = sm.f.sxy[o];
            float z = sm.f.sz[o];
            px[j] = xy.x; py[j] = xy.y; pz[j] = z;
            dmin[j] = __builtin_huge_valf();
            bx0 = fminf(bx0, xy.x); bx1 = fmaxf(bx1, xy.x);
            by0 = fminf(by0, xy.y); by1 = fmaxf(by1, xy.y);
            bz0 = fminf(bz0, z);    bz1 = fmaxf(bz1, z);
        }
        ull mykey = ((ull)0x7f800000u << 32);   // dmin part = +INF -> scans at t=0
        __syncthreads();

        for (int t = 0; t < MQ; t++) {
            int last;
            if (t) {
                const ulonglong2* pp = (const ulonglong2*)sm.f.part[(t - 1) & 1];
                ulonglong2 q0 = pp[0], q1 = pp[1], q2 = pp[2], q3 = pp[3];
                ull m0 = (q0.x > q0.y) ? q0.x : q0.y;
                ull m1 = (q1.x > q1.y) ? q1.x : q1.y;
                ull m2 = (q2.x > q2.y) ? q2.x : q2.y;
                ull m3 = (q3.x > q3.y) ? q3.x : q3.y;
                m0 = (m0 > m1) ? m0 : m1;
                m2 = (m2 > m3) ? m2 : m3;
                ull g = (m0 > m2) ? m0 : m2;
                last = ((int)(~(unsigned)g)) & (NPB - 1);
            } else {
                last = 0;
            }
            // wave 7 owns output publication: plain store per iter (latency hidden
            // by the vmcnt-free barrier), release-publish every 16 iters.
            if (tid == 448) {
                samp[b * MQ + t] = last;
                if ((t & 15) == 15)
                    __hip_atomic_store(&progress[b], t + 1, __ATOMIC_RELEASE,
                                       __HIP_MEMORY_SCOPE_AGENT);
            }
            float2 lxy = sm.f.sxy[last];
            float lx = lxy.x, ly = lxy.y, lz = sm.f.sz[last];

            // conservative lower bound of d2(last, any point in this thread's bbox)
            float ddx = fmaxf(fmaxf(bx0 - lx, lx - bx1), 0.0f);
            float ddy = fmaxf(fmaxf(by0 - ly, ly - by1), 0.0f);
            float ddz = fmaxf(fmaxf(bz0 - lz, lz - bz1), 0.0f);
            float dlb = ddx * ddx + ddy * ddy + ddz * ddz;
            float cm = __uint_as_float((unsigned)(mykey >> 32));

            if (__fmul_rn(0.999f, dlb) < cm) {
                ull bestk = 0;
                #pragma unroll
                for (int j = 0; j < 16; j++) {
                    float d = dist2(px[j], py[j], pz[j], lx, ly, lz);
                    float dm = fminf(dmin[j], d);
                    dmin[j] = dm;
                    ull kj = ((ull)__float_as_uint(dm) << 32) | (unsigned)(~orig[j]);
                    if (kj > bestk) bestk = kj;
                }
                mykey = bestk;
            }
            ull w = dpp_max_u64(mykey);
            if (lane == 63) sm.f.part[t & 1][wv] = w;
            LDS_BARRIER();   // orders the LDS partials; does NOT drain global stores
        }
        return;
    }

    // ================== consumers: ball query + MLP + tail outputs ==================
    const int c = blockIdx.x - NB;         // 0..247
    const int unit = tid >> 7;             // 0..3
    const int ut = tid & 127;              // thread-in-unit
    UnitSM& U = sm.u[unit];
    const int g = c * 4 + unit;            // global unit id, 0..991
    const float RR = (float)(0.1 * 0.1);

    // per-channel weights, hoisted across queries
    float w[68];
    #pragma unroll
    for (int f = 0; f < 67; f++) w[f] = W1[f * CD + ut];
    w[67] = 0.0f;
    const float bias = b1[ut];

    for (int qi = 0; qi < QITERS; qi++) {
        const int q = g + qi * NUNITS;
        const bool active = q < NQ;
        int b = 0, s = 0;
        const float* P = pos;
        float qx = 0.f, qy = 0.f, qz = 0.f;

        if (active) {
            b = q >> 11;
            const int tq = q & (MQ - 1);
            // HOT spin: keep the device busy (DVFS) and latency minimal
            while (__hip_atomic_load(&progress[b], __ATOMIC_ACQUIRE,
                                     __HIP_MEMORY_SCOPE_AGENT) < tq + 1) {}
            s = samp[q] & (NPB - 1);
            P = pos + (size_t)b * NPB * 3;
            qx = P[s * 3 + 0]; qy = P[s * 3 + 1]; qz = P[s * 3 + 2];
        }
        if (ut == 0) U.scnt = 0;
        __syncthreads();                                   // barrier 1

        if (active) {
            for (int p = ut; p < NPB; p += 128) {
                float xx = P[p * 3 + 0];
                float yy = P[p * 3 + 1];
                float zz = P[p * 3 + 2];
                float d2v = dist2(qx, qy, qz, xx, yy, zz);
                if (d2v <= RR) {
                    int slot = atomicAdd(&U.scnt, 1);
                    if (slot < CAP)
                        U.buf[slot] = ((ull)__float_as_uint(d2v) << 32) | (unsigned)p;
                }
            }
        }
        __syncthreads();                                   // barrier 2

        int n = 0, nk = 0;
        if (active) {
            n = U.scnt; if (n > CAP) n = CAP;
            nk = (n < KN) ? n : KN;
        }
        if (active && ut < 64) {
            if (n <= 64) {
                // fast path: 64-key bitonic sort in the unit's first wave
                ull key = (ut < n) ? U.buf[ut] : ~0ULL;
                #pragma unroll
                for (int k = 2; k <= 64; k <<= 1) {
                    #pragma unroll
                    for (int j = k >> 1; j > 0; j >>= 1) {
                        ull o = __shfl_xor(key, (unsigned)j, 64);
                        bool ascending = ((ut & k) == 0);
                        bool upper = ((ut & j) != 0);
                        bool keepMin = (ascending != upper);
                        ull mn = (o < key) ? o : key;
                        ull mx = (o < key) ? key : o;
                        key = keepMin ? mn : mx;
                    }
                }
                if (ut < nk) U.nb[ut] = ((int)(unsigned)key) & (NPB - 1);
            } else {
                // slow path (rare): nk rounds of wave-min selection
                ull ck[CAP / 64];
                #pragma unroll
                for (int i = 0; i < CAP / 64; i++) {
                    int sl = ut + i * 64;
                    ck[i] = (sl < n) ? U.buf[sl] : ~0ULL;
                }
                for (int r = 0; r < nk; r++) {
                    ull lm = ck[0];
                    int li = 0;
                    #pragma unroll
                    for (int i = 1; i < CAP / 64; i++) {
                        if (ck[i] < lm) { lm = ck[i]; li = i; }
                    }
                    ull gm = lm;
                    #pragma unroll
                    for (int off = 1; off < 64; off <<= 1) {
                        ull o = __shfl_xor(gm, off, 64);
                        gm = (o < gm) ? o : gm;
                    }
                    ull won = __ballot(lm == gm);
                    int wlane = __ffsll((long long)won) - 1;
                    if (ut == wlane) ck[li] = ~0ULL;
                    if (ut == 0) U.nb[r] = ((int)(unsigned)gm) & (NPB - 1);
                }
            }
        }
        __syncthreads();                                   // barrier 3

        if (active) {
            const int lane64 = ut & 63, half = ut >> 6;
            for (int k = half; k < nk; k += 2) {
                int p = U.nb[k];
                U.msg[k][lane64] = xin[((size_t)(b * NPB + p)) * FD + lane64];
            }
            if (ut < nk) {
                int p = U.nb[ut];
                U.msg[ut][64] = __fsub_rn(P[p * 3 + 0], qx);
                U.msg[ut][65] = __fsub_rn(P[p * 3 + 1], qy);
                U.msg[ut][66] = __fsub_rn(P[p * 3 + 2], qz);
                U.msg[ut][67] = 0.0f;
            }
        }
        __syncthreads();                                   // barrier 4

        if (active) {
            float acc = 0.0f;   // relu >= 0 and nk >= 1 (self), so 0 is the max identity
            for (int k = 0; k < nk; k++) {
                float s0 = 0.f, s1 = 0.f, s2 = 0.f, s3 = 0.f;
                #pragma unroll
                for (int f4 = 0; f4 < 17; f4++) {
                    float4 mv = *(const float4*)&U.msg[k][f4 * 4];
                    s0 = fmaf(mv.x, w[f4 * 4 + 0], s0);
                    s1 = fmaf(mv.y, w[f4 * 4 + 1], s1);
                    s2 = fmaf(mv.z, w[f4 * 4 + 2], s2);
                    s3 = fmaf(mv.w, w[f4 * 4 + 3], s3);
                }
                float h = (s0 + s1) + (s2 + s3) + bias;
                h = fmaxf(h, 0.0f);
                acc = fmaxf(acc, h);
            }
            out[(size_t)q * CD + ut] = acc;
            if (ut == 0) {
                float* qp = out + (size_t)NQ * CD;
                qp[q * 3 + 0] = qx;
                qp[q * 3 + 1] = qy;
                qp[q * 3 + 2] = qz;
                float* bo = qp + (size_t)NQ * 3;
                bo[q] = (float)b;
                float* io = bo + NQ;
                io[q] = (float)(b * NPB + s);
            }
        }
    }
}

extern "C" void kernel_launch(void* const* d_in, const int* in_sizes, int n_in,
                              void* d_out, int out_size, void* d_ws, size_t ws_size,
                              hipStream_t stream) {
    const float* x   = (const float*)d_in[0];
    const float* pos = (const float*)d_in[1];
    const float* W1  = (const float*)d_in[3];
    const float* b1  = (const float*)d_in[4];
    float* out = (float*)d_out;

    int* samp = (int*)d_ws;                     // NQ ints
    int* progress = samp + NQ;                  // NB ints
    unsigned int* sorted = (unsigned int*)(progress + NB);   // NB*NPB u32

    hipMemsetAsync(progress, 0, NB * sizeof(int), stream);
    presort_kernel<<<NB, 512, 0, stream>>>(pos, sorted);
    mega_kernel<<<NB + NCB, 512, 0, stream>>>(x, pos, W1, b1, sorted, samp, progress, out);
}